// Round 11
// baseline (340.594 us; speedup 1.0000x reference)
//
#include <hip/hip_runtime.h>
#include <hip/hip_bf16.h>

#define DEV __device__ __forceinline__

typedef __attribute__((ext_vector_type(8))) short bf16x8;
typedef __attribute__((ext_vector_type(4))) float f32x4;
typedef __attribute__((ext_vector_type(16))) float f32x16;

// ---------- helpers ----------
DEV short f2bf(float x){ __hip_bfloat16 h = __float2bfloat16(x); return *(short*)&h; }
DEV unsigned pack2bf(float a, float b){
  return (unsigned)(unsigned short)f2bf(a) | ((unsigned)(unsigned short)f2bf(b) << 16);
}
DEV float gelu_fast(float x){
  float z = 0.7978845608028654f*(x + 0.044715f*x*x*x);
  float e = __expf(-2.f*z);
  return x / (1.f + e);
}

#define SB 4096
#define DM 64
#define VSTR 664

// ---------- weight convert+transpose: f32 [K][N] -> bf16 [N][K], 32x32 tiles ----------
__global__ __launch_bounds__(256) void wconv(
    const float* __restrict__ wq, const float* __restrict__ wk,
    const float* __restrict__ wv, const float* __restrict__ wo,
    const float* __restrict__ w1, const float* __restrict__ w2,
    short* __restrict__ wqT, short* __restrict__ wkT,
    short* __restrict__ wvT, short* __restrict__ woT,
    short* __restrict__ w1T, short* __restrict__ w2T)
{
  int t = blockIdx.x, l = blockIdx.y;
  const float* src; short* dst; int K, N, kt, nt;
  if (t < 16) {
    int m = t >> 2, sub = t & 3; kt = sub >> 1; nt = sub & 1; K = 64; N = 64;
    const float* s4[4] = {wq, wk, wv, wo};
    short*       d4[4] = {wqT, wkT, wvT, woT};
    src = s4[m] + l*4096; dst = d4[m] + l*4096;
  } else if (t < 48) {
    kt = (t-16) >> 4; nt = (t-16) & 15; K = 64; N = 512;
    src = w1 + l*32768; dst = w1T + l*32768;
  } else {
    kt = (t-48) >> 1; nt = (t-48) & 1; K = 512; N = 64;
    src = w2 + l*32768; dst = w2T + l*32768;
  }
  __shared__ float lds[32][33];
  int tx = threadIdx.x & 31, ty = threadIdx.x >> 5;
  int k0 = kt*32, n0 = nt*32;
  #pragma unroll
  for (int j=0;j<4;++j) lds[ty+8*j][tx] = src[(size_t)(k0+ty+8*j)*N + n0 + tx];
  __syncthreads();
  #pragma unroll
  for (int j=0;j<4;++j) {
    int nn = ty+8*j;
    dst[(size_t)(n0+nn)*K + k0 + tx] = f2bf(lds[tx][nn]);
  }
}

// ---------- building blocks ----------
DEV void make_frags_ln(const float* rowp, float mean, float inv,
    const float* __restrict__ s, const float* __restrict__ b, int kq,
    bf16x8& a0, bf16x8& a1){
  #pragma unroll
  for (int i=0;i<8;++i) a0[i] = f2bf((rowp[kq*8+i]-mean)*inv*s[kq*8+i]+b[kq*8+i]);
  #pragma unroll
  for (int i=0;i<8;++i) a1[i] = f2bf((rowp[32+kq*8+i]-mean)*inv*s[32+kq*8+i]+b[32+kq*8+i]);
}
// 16x16 col-tile, K=64 (2 MFMA), B from bf16 [N][64] transposed weights
DEV void gemm1(const bf16x8& a0, const bf16x8& a1, const short* __restrict__ WT,
               int col0, int kq, int r, f32x4& acc){
  const short* wp = WT + (size_t)(col0 + r)*64 + kq*8;
  bf16x8 b0  = *(const bf16x8*)(wp);
  bf16x8 b1v = *(const bf16x8*)(wp + 32);
  acc = __builtin_amdgcn_mfma_f32_16x16x32_bf16(a0, b0,  acc, 0, 0, 0);
  acc = __builtin_amdgcn_mfma_f32_16x16x32_bf16(a1, b1v, acc, 0, 0, 0);
}

// ---------- fused layer kernel v5: ONE WAVE per block, 8 ROWS, zero barriers ----------
// MFMA tile rows 8-15 duplicate rows 0-7 (lanes r>=8 read row r-8); C rows 8-15 are
// exact duplicates and are not stored (kq<2 lanes store rows 0-7).
template<bool EMBED, bool LAST>
__global__ __launch_bounds__(64,4) void fused1w(
    const int* __restrict__ x, const float* __restrict__ emb,
    const unsigned short* __restrict__ ab,
    const short* __restrict__ woT, const float* __restrict__ bo,
    const float* __restrict__ ln2s, const float* __restrict__ ln2b,
    const short* __restrict__ w1T, const float* __restrict__ b1,
    const short* __restrict__ w2T, const float* __restrict__ b2,
    const float* __restrict__ lns, const float* __restrict__ lnb,   // LN1(next) or LNf
    const short* __restrict__ wqT, const short* __restrict__ wkT, const short* __restrict__ wvT,
    const float* __restrict__ bq, const float* __restrict__ bk, const float* __restrict__ bv,
    unsigned short* __restrict__ qo, unsigned short* __restrict__ ko, unsigned short* __restrict__ vo,
    float* __restrict__ h, float* __restrict__ part)
{
  __shared__ float hN[8][68];
  __shared__ short mid[8][264];
  __shared__ float mu[8], iv[8];

  const int bid = blockIdx.x;
  const int row_g0 = bid * 8;
  const int lane = threadIdx.x;
  const int r16 = lane & 15, kq = lane >> 4;
  const int rl = r16 & 7;                      // duplicated A-row
  const int srow = lane >> 3, sd8 = lane & 7;  // stats/embed: 8 lanes/row, 8 vals each

  if constexpr (EMBED) {
    int tg = row_g0 + srow;
    int s = tg & (SB-1);
    int tok = x[tg];
    #pragma unroll
    for (int i=0;i<8;++i) {
      int d = sd8*8 + i;
      float fe = (float)(d & ~1) * (1.0f/64.0f);
      float invk = __expf(-9.210340371976184f * fe);
      float ang = (float)s * invk;
      float pe = (d & 1) ? __cosf(ang) : __sinf(ang);
      float val = emb[tok*DM + d] + pe;
      hN[srow][d] = val;
      h[(size_t)tg*DM + d] = val;
    }
  } else {
    // attn-out projection (8x64) + residual
    const short* abp = (const short*)(ab + (size_t)(row_g0 + rl)*DM + kq*8);
    bf16x8 a0 = *(const bf16x8*)abp;
    bf16x8 a1 = *(const bf16x8*)(abp + 32);
    f32x4 ao[4];
    #pragma unroll
    for (int ct=0; ct<4; ++ct) ao[ct] = (f32x4){0.f,0.f,0.f,0.f};
    #pragma unroll
    for (int ct=0; ct<4; ++ct) gemm1(a0, a1, woT, ct*16, kq, r16, ao[ct]);
    if (kq < 2) {
      #pragma unroll
      for (int ct=0; ct<4; ++ct) {
        int col = ct*16 + r16;
        #pragma unroll
        for (int j=0;j<4;++j) {
          int orow = kq*4 + j;
          hN[orow][col] = ao[ct][j] + bo[col] + h[(size_t)(row_g0+orow)*DM + col];
        }
      }
    }
  }

  // LN stats #1
  {
    const float* q = &hN[srow][sd8*8];
    float v[8];
    float sum = 0.f;
    #pragma unroll
    for (int i=0;i<8;++i){ v[i] = q[i]; sum += v[i]; }
    sum += __shfl_xor(sum, 1, 64); sum += __shfl_xor(sum, 2, 64); sum += __shfl_xor(sum, 4, 64);
    float mean = sum * (1.f/64.f);
    float sq = 0.f;
    #pragma unroll
    for (int i=0;i<8;++i){ float d = v[i]-mean; sq += d*d; }
    sq += __shfl_xor(sq, 1, 64); sq += __shfl_xor(sq, 2, 64); sq += __shfl_xor(sq, 4, 64);
    if (sd8 == 0) { mu[srow] = mean; iv[srow] = rsqrtf(sq*(1.f/64.f) + 1e-6f); }
  }

  if constexpr (!EMBED) {
    // ---- FFN: fc1 (2 chunks of 256 cols) -> mid -> fc2 accumulate ----
    bf16x8 a0, a1;
    make_frags_ln(&hN[rl][0], mu[rl], iv[rl], ln2s, ln2b, kq, a0, a1);
    f32x4 acc2[4];
    #pragma unroll
    for (int ct=0; ct<4; ++ct) acc2[ct] = (f32x4){0.f,0.f,0.f,0.f};
    #pragma unroll
    for (int c=0; c<2; ++c) {
      #pragma unroll
      for (int g=0; g<4; ++g) {
        f32x4 acc1[4];
        #pragma unroll
        for (int t=0;t<4;++t) acc1[t] = (f32x4){0.f,0.f,0.f,0.f};
        #pragma unroll
        for (int t=0;t<4;++t) {
          int colt = c*256 + g*64 + t*16;
          const short* wp = w1T + (size_t)(colt + r16)*64 + kq*8;
          bf16x8 b0  = *(const bf16x8*)(wp);
          bf16x8 b1v = *(const bf16x8*)(wp + 32);
          acc1[t] = __builtin_amdgcn_mfma_f32_16x16x32_bf16(a0, b0,  acc1[t], 0, 0, 0);
          acc1[t] = __builtin_amdgcn_mfma_f32_16x16x32_bf16(a1, b1v, acc1[t], 0, 0, 0);
        }
        if (kq < 2) {
          #pragma unroll
          for (int t=0;t<4;++t) {
            int col = c*256 + g*64 + t*16 + r16;
            int lcol = g*64 + t*16 + r16;
            float bb = b1[col];
            #pragma unroll
            for (int j=0;j<4;++j)
              mid[kq*4 + j][lcol] = f2bf(gelu_fast(acc1[t][j] + bb));
          }
        }
      }
      // fc2 partial over this 256-wide k chunk
      #pragma unroll
      for (int ks=0; ks<8; ++ks) {
        bf16x8 af = *(const bf16x8*)(&mid[rl][ks*32 + kq*8]);
        #pragma unroll
        for (int ct=0; ct<4; ++ct) {
          const short* wp = w2T + (size_t)(ct*16 + r16)*512 + c*256 + ks*32 + kq*8;
          bf16x8 bw = *(const bf16x8*)(wp);
          acc2[ct] = __builtin_amdgcn_mfma_f32_16x16x32_bf16(af, bw, acc2[ct], 0, 0, 0);
        }
      }
    }
    // + bias + residual; update hN and global h
    if (kq < 2) {
      #pragma unroll
      for (int ct=0; ct<4; ++ct) {
        int col = ct*16 + r16;
        float bb = b2[col];
        #pragma unroll
        for (int j=0;j<4;++j) {
          int orow = kq*4 + j;
          float val = acc2[ct][j] + bb + hN[orow][col];
          hN[orow][col] = val;
          h[(size_t)(row_g0+orow)*DM + col] = val;
        }
      }
    }
    // LN stats #2
    {
      const float* q = &hN[srow][sd8*8];
      float v[8];
      float sum = 0.f;
      #pragma unroll
      for (int i=0;i<8;++i){ v[i] = q[i]; sum += v[i]; }
      sum += __shfl_xor(sum, 1, 64); sum += __shfl_xor(sum, 2, 64); sum += __shfl_xor(sum, 4, 64);
      float mean = sum * (1.f/64.f);
      float sq = 0.f;
      #pragma unroll
      for (int i=0;i<8;++i){ float d = v[i]-mean; sq += d*d; }
      sq += __shfl_xor(sq, 1, 64); sq += __shfl_xor(sq, 2, 64); sq += __shfl_xor(sq, 4, 64);
      if (sd8 == 0) { mu[srow] = mean; iv[srow] = rsqrtf(sq*(1.f/64.f) + 1e-6f); }
    }
  }

  if constexpr (!LAST) {
    // qkv projection (8x64 x3)
    const float qscale = 0.35355339059327373f;
    bf16x8 a0, a1;
    make_frags_ln(&hN[rl][0], mu[rl], iv[rl], lns, lnb, kq, a0, a1);
    f32x4 aq[4], ak[4], av[4];
    #pragma unroll
    for (int ct=0; ct<4; ++ct) {
      aq[ct] = (f32x4){0.f,0.f,0.f,0.f};
      ak[ct] = (f32x4){0.f,0.f,0.f,0.f};
      av[ct] = (f32x4){0.f,0.f,0.f,0.f};
    }
    #pragma unroll
    for (int ct=0; ct<4; ++ct) {
      gemm1(a0, a1, wqT, ct*16, kq, r16, aq[ct]);
      gemm1(a0, a1, wkT, ct*16, kq, r16, ak[ct]);
      gemm1(a0, a1, wvT, ct*16, kq, r16, av[ct]);
    }
    if (kq < 2) {
      #pragma unroll
      for (int ct=0; ct<4; ++ct) {
        int col = ct*16 + r16;
        float bqv = bq[col], bkv = bk[col], bvv = bv[col];
        #pragma unroll
        for (int j=0;j<4;++j) {
          int orow = kq*4 + j;
          size_t oi = (size_t)(row_g0 + orow)*DM + col;
          qo[oi] = (unsigned short)f2bf((aq[ct][j] + bqv)*qscale);
          ko[oi] = (unsigned short)f2bf(ak[ct][j] + bkv);
          vo[oi] = (unsigned short)f2bf(av[ct][j] + bvv);
        }
      }
    }
  } else {
    // final LN in place + pool partial (8 rows)
    float mean = mu[srow], inv = iv[srow];
    #pragma unroll
    for (int i=0;i<8;++i) {
      int d = sd8*8 + i;
      hN[srow][d] = (hN[srow][d]-mean)*inv*lns[d] + lnb[d];
    }
    float s = 0.f;
    #pragma unroll
    for (int rr=0; rr<8; ++rr) s += hN[rr][lane];
    part[bid*64 + lane] = s;
  }
}

// ---------- sliding-window attention (MFMA, unchanged) ----------
__global__ __launch_bounds__(256) void attn_kernel(
    const unsigned short* __restrict__ qg_,
    const unsigned short* __restrict__ kg_,
    const unsigned short* __restrict__ vg_,
    __hip_bfloat16* __restrict__ out)
{
  const int qblk = blockIdx.x, bh = blockIdx.y;
  const int b = bh >> 3, hh = bh & 7;
  const int tid = threadIdx.x;
  const int q0b = qblk << 7;
  const int kbase = q0b - 256;

  __shared__ unsigned short Ks[640*8];
  __shared__ unsigned short Vs[8*VSTR];

  const unsigned short* kgp = kg_ + ((size_t)b*SB)*DM + hh*8;
  const unsigned short* vgp = vg_ + ((size_t)b*SB)*DM + hh*8;

  for (int e = tid; e < 640; e += 256) {
    int g = kbase + e;
    uint4 kv = make_uint4(0,0,0,0), vv = make_uint4(0,0,0,0);
    if ((unsigned)g < (unsigned)SB) {
      kv = *(const uint4*)(kgp + (size_t)g*DM);
      vv = *(const uint4*)(vgp + (size_t)g*DM);
    }
    *(uint4*)(Ks + e*8) = kv;
    const unsigned short* pv = (const unsigned short*)&vv;
    #pragma unroll
    for (int d = 0; d < 8; ++d) Vs[d*VSTR + e] = pv[d];
  }
  __syncthreads();

  const int w = tid >> 6;
  const int lane = tid & 63;
  const int qc = lane & 31;
  const int hf = lane >> 5;
  const int qglob = q0b + 32*w + qc;

  bf16x8 qfrag = {};
  if (hf == 0) qfrag = *(const bf16x8*)(qg_ + ((size_t)b*SB + qglob)*DM + hh*8);

  f32x16 oacc = {};
  float lacc = 0.f;

  for (int t = 0; t <= 16; ++t) {
    const int k0l = 32*w + 32*t;
    const int k0g = kbase + k0l;
    if (k0g > SB-1 || k0g + 31 < 0) continue;

    bf16x8 kfrag = {};
    if (hf == 0) kfrag = *(const bf16x8*)(Ks + (k0l + qc)*8);

    f32x16 s = __builtin_amdgcn_mfma_f32_32x32x16_bf16(kfrag, qfrag, (f32x16){}, 0, 0, 0);

    float pp[16];
    bool needmask = (t == 0) | (t == 16) | (k0g < 0) | (k0g + 31 > SB-1);
    if (needmask) {
      #pragma unroll
      for (int rr = 0; rr < 16; ++rr) {
        int klg = k0g + (rr&3) + 8*(rr>>2) + 4*hf;
        bool ok = ((unsigned)(klg - qglob + 256) <= 512u) && ((unsigned)klg < (unsigned)SB);
        pp[rr] = ok ? __expf(s[rr]) : 0.f;
      }
    } else {
      #pragma unroll
      for (int rr = 0; rr < 16; ++rr) pp[rr] = __expf(s[rr]);
    }
    #pragma unroll
    for (int rr = 0; rr < 16; ++rr) lacc += pp[rr];

    unsigned pk[8];
    #pragma unroll
    for (int j = 0; j < 8; ++j) pk[j] = pack2bf(pp[2*j], pp[2*j+1]);
    unsigned sw[8];
    #pragma unroll
    for (int j = 0; j < 8; ++j) sw[j] = __shfl_xor(pk[j], 32, 64);

    union { unsigned u[4]; bf16x8 v; } pb1;
    pb1.u[0] = hf ? sw[2] : pk[0];
    pb1.u[1] = hf ? sw[3] : pk[1];
    pb1.u[2] = hf ? pk[2] : sw[0];
    pb1.u[3] = hf ? pk[3] : sw[1];
    bf16x8 va1 = {};
    if (qc < 8) va1 = *(const bf16x8*)(Vs + qc*VSTR + k0l + 8*hf);
    oacc = __builtin_amdgcn_mfma_f32_32x32x16_bf16(va1, pb1.v, oacc, 0, 0, 0);

    union { unsigned u[4]; bf16x8 v; } pb2;
    pb2.u[0] = hf ? sw[6] : pk[4];
    pb2.u[1] = hf ? sw[7] : pk[5];
    pb2.u[2] = hf ? pk[6] : sw[4];
    pb2.u[3] = hf ? pk[7] : sw[5];
    bf16x8 va2 = {};
    if (qc < 8) va2 = *(const bf16x8*)(Vs + qc*VSTR + k0l + 16 + 8*hf);
    oacc = __builtin_amdgcn_mfma_f32_32x32x16_bf16(va2, pb2.v, oacc, 0, 0, 0);
  }

  float lsum = lacc + __shfl_xor(lacc, 32, 64);
  float rcp = 1.f / lsum;
  unsigned short ov[4];
  #pragma unroll
  for (int j = 0; j < 4; ++j) ov[j] = (unsigned short)f2bf(oacc[j] * rcp);
  *(uint2*)(out + ((size_t)b*SB + qglob)*DM + hh*8 + 4*hf) = *(uint2*)ov;
}

// ---------- pool finalize + classifier ----------
__global__ __launch_bounds__(256) void pool_finalize(const float* __restrict__ part,
    const float* __restrict__ wcls, const float* __restrict__ bcls, float* __restrict__ out)
{
  int tid = threadIdx.x;
  int b = tid >> 6, d = tid & 63;
  float sum = 0.f;
  #pragma unroll 8
  for (int i = 0; i < 512; ++i) sum += part[(b*512 + i)*64 + d];
  __shared__ float pooled[4][64];
  pooled[b][d] = sum * (1.f/4096.f);
  __syncthreads();
  if (tid < 40) {
    int bb = tid / 10, c = tid % 10;
    float acc = bcls[c];
    #pragma unroll
    for (int dd = 0; dd < 64; ++dd) acc = fmaf(pooled[bb][dd], wcls[dd*10 + c], acc);
    out[tid] = acc;
  }
}

// ---------- launcher ----------
extern "C" void kernel_launch(void* const* d_in, const int* in_sizes, int n_in,
                              void* d_out, int out_size, void* d_ws, size_t ws_size,
                              hipStream_t stream)
{
  const int*   x    = (const int*)d_in[0];
  const float* emb  = (const float*)d_in[1];
  const float* wq   = (const float*)d_in[2];
  const float* bq   = (const float*)d_in[3];
  const float* wk   = (const float*)d_in[4];
  const float* bk   = (const float*)d_in[5];
  const float* wv   = (const float*)d_in[6];
  const float* bv   = (const float*)d_in[7];
  const float* wo   = (const float*)d_in[8];
  const float* bo   = (const float*)d_in[9];
  const float* ln1s = (const float*)d_in[10];
  const float* ln1b = (const float*)d_in[11];
  const float* ln2s = (const float*)d_in[12];
  const float* ln2b = (const float*)d_in[13];
  const float* w1   = (const float*)d_in[14];
  const float* b1   = (const float*)d_in[15];
  const float* w2   = (const float*)d_in[16];
  const float* b2   = (const float*)d_in[17];
  const float* lnfs = (const float*)d_in[18];
  const float* lnfb = (const float*)d_in[19];
  const float* wcls = (const float*)d_in[20];
  const float* bcls = (const float*)d_in[21];
  float* out = (float*)d_out;

  char* wsb = (char*)d_ws;
  const size_t MB = 1u << 20;
  float* h  = (float*)(wsb);                             // 4 MB f32 [16384][64]
  unsigned short* qb2 = (unsigned short*)(wsb + 4*MB);   // 2 MB bf16
  unsigned short* kb2 = (unsigned short*)(wsb + 6*MB);
  unsigned short* vb2 = (unsigned short*)(wsb + 8*MB);
  unsigned short* ab  = (unsigned short*)(wsb + 10*MB);  // 2 MB bf16
  short* wqT = (short*)(wsb + 12*MB);
  short* wkT = (short*)(wsb + 12*MB + 32*1024);
  short* wvT = (short*)(wsb + 12*MB + 64*1024);
  short* woT = (short*)(wsb + 12*MB + 96*1024);
  short* w1T = (short*)(wsb + 12*MB + 128*1024);         // 256 KB
  short* w2T = (short*)(wsb + 12*MB + 384*1024);         // 256 KB
  float* part = (float*)(wsb + 13*MB);                   // 512 KB

  wconv<<<dim3(80,4),256,0,stream>>>(wq,wk,wv,wo,w1,w2, wqT,wkT,wvT,woT,w1T,w2T);

  // head: embed + LN1(l0) + qkv(l0)
  fused1w<true,false><<<2048,64,0,stream>>>(
      x, emb, nullptr,
      nullptr, nullptr, nullptr, nullptr,
      nullptr, nullptr, nullptr, nullptr,
      ln1s, ln1b,
      wqT, wkT, wvT, bq, bk, bv,
      qb2, kb2, vb2, h, nullptr);

  for (int l = 0; l < 4; ++l) {
    attn_kernel<<<dim3(32,32),256,0,stream>>>(qb2, kb2, vb2, (__hip_bfloat16*)ab);
    if (l < 3) {
      fused1w<false,false><<<2048,64,0,stream>>>(
          nullptr, nullptr, ab,
          woT+4096*l, bo+64*l, ln2s+64*l, ln2b+64*l,
          w1T+32768*l, b1+512*l, w2T+32768*l, b2+64*l,
          ln1s+64*(l+1), ln1b+64*(l+1),
          wqT+4096*(l+1), wkT+4096*(l+1), wvT+4096*(l+1),
          bq+64*(l+1), bk+64*(l+1), bv+64*(l+1),
          qb2, kb2, vb2, h, nullptr);
    } else {
      fused1w<false,true><<<2048,64,0,stream>>>(
          nullptr, nullptr, ab,
          woT+4096*l, bo+64*l, ln2s+64*l, ln2b+64*l,
          w1T+32768*l, b1+512*l, w2T+32768*l, b2+64*l,
          lnfs, lnfb,
          nullptr, nullptr, nullptr, nullptr, nullptr, nullptr,
          nullptr, nullptr, nullptr, h, part);
    }
  }
  pool_finalize<<<1,256,0,stream>>>(part, wcls, bcls, out);
}

// Round 12
// 222.781 us; speedup vs baseline: 1.5288x; 1.5288x over previous
//
#include <hip/hip_runtime.h>
#include <hip/hip_bf16.h>

#define DEV __device__ __forceinline__

typedef __attribute__((ext_vector_type(8))) short bf16x8;
typedef __attribute__((ext_vector_type(4))) float f32x4;
typedef __attribute__((ext_vector_type(16))) float f32x16;

// ---------- helpers ----------
DEV short f2bf(float x){ __hip_bfloat16 h = __float2bfloat16(x); return *(short*)&h; }
DEV unsigned pack2bf(float a, float b){
  return (unsigned)(unsigned short)f2bf(a) | ((unsigned)(unsigned short)f2bf(b) << 16);
}
DEV float gelu_fast(float x){
  float z = 0.7978845608028654f*(x + 0.044715f*x*x*x);
  float e = __expf(-2.f*z);
  return x / (1.f + e);
}

#define SB 4096
#define DM 64
#define VSTR 664

// ---------- weight convert+transpose: f32 [K][N] -> bf16 [N][K], 32x32 tiles ----------
__global__ __launch_bounds__(256) void wconv(
    const float* __restrict__ wq, const float* __restrict__ wk,
    const float* __restrict__ wv, const float* __restrict__ wo,
    const float* __restrict__ w1, const float* __restrict__ w2,
    short* __restrict__ wqT, short* __restrict__ wkT,
    short* __restrict__ wvT, short* __restrict__ woT,
    short* __restrict__ w1T, short* __restrict__ w2T)
{
  int t = blockIdx.x, l = blockIdx.y;
  const float* src; short* dst; int K, N, kt, nt;
  if (t < 16) {
    int m = t >> 2, sub = t & 3; kt = sub >> 1; nt = sub & 1; K = 64; N = 64;
    const float* s4[4] = {wq, wk, wv, wo};
    short*       d4[4] = {wqT, wkT, wvT, woT};
    src = s4[m] + l*4096; dst = d4[m] + l*4096;
  } else if (t < 48) {
    kt = (t-16) >> 4; nt = (t-16) & 15; K = 64; N = 512;
    src = w1 + l*32768; dst = w1T + l*32768;
  } else {
    kt = (t-48) >> 1; nt = (t-48) & 1; K = 512; N = 64;
    src = w2 + l*32768; dst = w2T + l*32768;
  }
  __shared__ float lds[32][33];
  int tx = threadIdx.x & 31, ty = threadIdx.x >> 5;
  int k0 = kt*32, n0 = nt*32;
  #pragma unroll
  for (int j=0;j<4;++j) lds[ty+8*j][tx] = src[(size_t)(k0+ty+8*j)*N + n0 + tx];
  __syncthreads();
  #pragma unroll
  for (int j=0;j<4;++j) {
    int nn = ty+8*j;
    dst[(size_t)(n0+nn)*K + k0 + tx] = f2bf(lds[tx][nn]);
  }
}

// ---------- building blocks ----------
DEV void make_frags_ln(const float* rowp, float mean, float inv,
    const float* __restrict__ s, const float* __restrict__ b, int kq,
    bf16x8& a0, bf16x8& a1){
  #pragma unroll
  for (int i=0;i<8;++i) a0[i] = f2bf((rowp[kq*8+i]-mean)*inv*s[kq*8+i]+b[kq*8+i]);
  #pragma unroll
  for (int i=0;i<8;++i) a1[i] = f2bf((rowp[32+kq*8+i]-mean)*inv*s[32+kq*8+i]+b[32+kq*8+i]);
}

// ---------- fused layer kernel v6: 32 rows, 4 waves, batched+prefetched loads ----------
// wave w: rows wr0=(w>>1)*16, cols cc0=(w&1)*32 for attnout/fc2/qkv; fc1 cols 128w..+128.
template<bool EMBED, bool LAST>
__global__ __launch_bounds__(256,2) void fused_kernel(
    const int* __restrict__ x, const float* __restrict__ emb,
    const unsigned short* __restrict__ ab,
    const short* __restrict__ woT, const float* __restrict__ bo,
    const float* __restrict__ ln2s, const float* __restrict__ ln2b,
    const short* __restrict__ w1T, const float* __restrict__ b1,
    const short* __restrict__ w2T, const float* __restrict__ b2,
    const float* __restrict__ lns, const float* __restrict__ lnb,   // LN1(next) or LNf
    const short* __restrict__ wqT, const short* __restrict__ wkT, const short* __restrict__ wvT,
    const float* __restrict__ bq, const float* __restrict__ bk, const float* __restrict__ bv,
    unsigned short* __restrict__ qo, unsigned short* __restrict__ ko, unsigned short* __restrict__ vo,
    float* __restrict__ h, float* __restrict__ part)
{
  __shared__ float hN[32][76];
  __shared__ short mid[32][520];
  __shared__ float mu[32], iv[32];

  const int bid = blockIdx.x;
  const int row_g0 = bid * 32;
  const int tid = threadIdx.x;
  const int w = tid >> 6, lane = tid & 63;
  const int r = lane & 15, kq = lane >> 4;
  const int wr0 = (w >> 1) * 16;
  const int cc0 = (w & 1) * 32;
  const int srow = tid >> 3, sdq = tid & 7;   // stats/embed: 8 threads/row

  // ---- PREFETCH: fc1 weights (no deps) — in flight under attnout+LN ----
  bf16x8 w1b[16];
  if constexpr (!EMBED) {
    #pragma unroll
    for (int ct=0; ct<8; ++ct) {
      const short* wp = w1T + (size_t)(w*128 + ct*16 + r)*64 + kq*8;
      w1b[2*ct]   = *(const bf16x8*)(wp);
      w1b[2*ct+1] = *(const bf16x8*)(wp + 32);
    }
  }

  if constexpr (EMBED) {
    int tg = row_g0 + srow;
    int s = tg & (SB-1);
    int tok = x[tg];
    #pragma unroll
    for (int i=0;i<8;++i) {
      int d = sdq*8 + i;
      float fe = (float)(d & ~1) * (1.0f/64.0f);
      float invk = __expf(-9.210340371976184f * fe);
      float ang = (float)s * invk;
      float pe = (d & 1) ? __cosf(ang) : __sinf(ang);
      float val = emb[tok*DM + d] + pe;
      hN[srow][d] = val;
      h[(size_t)tg*DM + d] = val;
    }
  } else {
    // attn-out projection + residual (batched loads)
    const short* abp = (const short*)(ab + (size_t)(row_g0 + wr0 + r)*DM + kq*8);
    bf16x8 a0 = *(const bf16x8*)abp;
    bf16x8 a1 = *(const bf16x8*)(abp + 32);
    const short* wp0 = woT + (size_t)(cc0 + r)*64 + kq*8;
    const short* wp1 = woT + (size_t)(cc0 + 16 + r)*64 + kq*8;
    bf16x8 wb0 = *(const bf16x8*)(wp0);
    bf16x8 wb1 = *(const bf16x8*)(wp0 + 32);
    bf16x8 wb2 = *(const bf16x8*)(wp1);
    bf16x8 wb3 = *(const bf16x8*)(wp1 + 32);
    f32x4 acc[2] = {(f32x4){0,0,0,0},(f32x4){0,0,0,0}};
    acc[0] = __builtin_amdgcn_mfma_f32_16x16x32_bf16(a0, wb0, acc[0], 0, 0, 0);
    acc[0] = __builtin_amdgcn_mfma_f32_16x16x32_bf16(a1, wb1, acc[0], 0, 0, 0);
    acc[1] = __builtin_amdgcn_mfma_f32_16x16x32_bf16(a0, wb2, acc[1], 0, 0, 0);
    acc[1] = __builtin_amdgcn_mfma_f32_16x16x32_bf16(a1, wb3, acc[1], 0, 0, 0);
    #pragma unroll
    for (int ct=0; ct<2; ++ct) {
      int col = cc0 + ct*16 + r;
      #pragma unroll
      for (int j=0;j<4;++j) {
        int rl = wr0 + kq*4 + j;
        hN[rl][col] = acc[ct][j] + bo[col] + h[(size_t)(row_g0+rl)*DM + col];
      }
    }
  }
  __syncthreads();

  // LN stats (LN1 for EMBED, LN2 otherwise)
  {
    const float* p = &hN[srow][sdq*8];
    float v[8];
    #pragma unroll
    for (int i=0;i<8;++i) v[i] = p[i];
    float sum = 0.f;
    #pragma unroll
    for (int i=0;i<8;++i) sum += v[i];
    sum += __shfl_xor(sum, 1, 64); sum += __shfl_xor(sum, 2, 64); sum += __shfl_xor(sum, 4, 64);
    float mean = sum * (1.f/64.f);
    float sq = 0.f;
    #pragma unroll
    for (int i=0;i<8;++i) { float d = v[i]-mean; sq += d*d; }
    sq += __shfl_xor(sq, 1, 64); sq += __shfl_xor(sq, 2, 64); sq += __shfl_xor(sq, 4, 64);
    if (sdq == 0) { mu[srow] = mean; iv[srow] = rsqrtf(sq*(1.f/64.f) + 1e-6f); }
  }
  __syncthreads();

  // qkv weight prefetch storage (issued later, used at the end)
  bf16x8 qwb[12];

  if constexpr (!EMBED) {
    // ---- fc1: wave w covers cols [128w, 128w+128), rows 0..31 (weights prefetched) ----
    bf16x8 a00, a01, a10, a11;
    make_frags_ln(&hN[r][0],    mu[r],    iv[r],    ln2s, ln2b, kq, a00, a01);
    make_frags_ln(&hN[16+r][0], mu[16+r], iv[16+r], ln2s, ln2b, kq, a10, a11);
    f32x4 acc1[2][8];
    #pragma unroll
    for (int rh=0; rh<2; ++rh)
      #pragma unroll
      for (int ct=0; ct<8; ++ct) acc1[rh][ct] = (f32x4){0.f,0.f,0.f,0.f};
    #pragma unroll
    for (int ct=0; ct<8; ++ct) {
      acc1[0][ct] = __builtin_amdgcn_mfma_f32_16x16x32_bf16(a00, w1b[2*ct],   acc1[0][ct], 0, 0, 0);
      acc1[0][ct] = __builtin_amdgcn_mfma_f32_16x16x32_bf16(a01, w1b[2*ct+1], acc1[0][ct], 0, 0, 0);
      acc1[1][ct] = __builtin_amdgcn_mfma_f32_16x16x32_bf16(a10, w1b[2*ct],   acc1[1][ct], 0, 0, 0);
      acc1[1][ct] = __builtin_amdgcn_mfma_f32_16x16x32_bf16(a11, w1b[2*ct+1], acc1[1][ct], 0, 0, 0);
    }

    // ---- PREFETCH: qkv weights (hidden under mid-store + barrier + fc2) ----
    if constexpr (!LAST) {
      #pragma unroll
      for (int m=0;m<3;++m){
        const short* WT = m==0?wqT:(m==1?wkT:wvT);
        const short* qp0 = WT + (size_t)(cc0 + r)*64 + kq*8;
        const short* qp1 = WT + (size_t)(cc0 + 16 + r)*64 + kq*8;
        qwb[4*m+0] = *(const bf16x8*)(qp0);
        qwb[4*m+1] = *(const bf16x8*)(qp0 + 32);
        qwb[4*m+2] = *(const bf16x8*)(qp1);
        qwb[4*m+3] = *(const bf16x8*)(qp1 + 32);
      }
    }

    #pragma unroll
    for (int ct=0; ct<8; ++ct) {
      int col = w*128 + ct*16 + r;
      float bb = b1[col];
      #pragma unroll
      for (int rh=0; rh<2; ++rh)
        #pragma unroll
        for (int j=0; j<4; ++j)
          mid[rh*16 + kq*4 + j][col] = f2bf(gelu_fast(acc1[rh][ct][j] + bb));
    }
    __syncthreads();

    // ---- fc2: wave quadrant (wr0, cc0), K=512 — all loads issued up front ----
    bf16x8 w2b[32];
    bf16x8 afb[16];
    #pragma unroll
    for (int ks=0; ks<16; ++ks) {
      const short* wp = w2T + (size_t)(cc0 + r)*512 + ks*32 + kq*8;
      w2b[2*ks]   = *(const bf16x8*)(wp);
      w2b[2*ks+1] = *(const bf16x8*)(wp + (size_t)16*512);
      afb[ks]     = *(const bf16x8*)(&mid[wr0 + r][ks*32 + kq*8]);
    }
    f32x4 acc2[2] = {(f32x4){0,0,0,0},(f32x4){0,0,0,0}};
    #pragma unroll
    for (int ks=0; ks<16; ++ks) {
      acc2[0] = __builtin_amdgcn_mfma_f32_16x16x32_bf16(afb[ks], w2b[2*ks],   acc2[0], 0, 0, 0);
      acc2[1] = __builtin_amdgcn_mfma_f32_16x16x32_bf16(afb[ks], w2b[2*ks+1], acc2[1], 0, 0, 0);
    }
    #pragma unroll
    for (int ct=0; ct<2; ++ct) {
      int col = cc0 + ct*16 + r;
      float bb = b2[col];
      #pragma unroll
      for (int j=0; j<4; ++j) {
        int rl = wr0 + kq*4 + j;
        float val = acc2[ct][j] + bb + hN[rl][col];
        hN[rl][col] = val;
        h[(size_t)(row_g0+rl)*DM + col] = val;
      }
    }
    __syncthreads();

    // LN stats for LN1(next) / LNf
    {
      const float* p = &hN[srow][sdq*8];
      float v[8];
      #pragma unroll
      for (int i=0;i<8;++i) v[i] = p[i];
      float sum = 0.f;
      #pragma unroll
      for (int i=0;i<8;++i) sum += v[i];
      sum += __shfl_xor(sum, 1, 64); sum += __shfl_xor(sum, 2, 64); sum += __shfl_xor(sum, 4, 64);
      float mean = sum * (1.f/64.f);
      float sq = 0.f;
      #pragma unroll
      for (int i=0;i<8;++i) { float d = v[i]-mean; sq += d*d; }
      sq += __shfl_xor(sq, 1, 64); sq += __shfl_xor(sq, 2, 64); sq += __shfl_xor(sq, 4, 64);
      if (sdq == 0) { mu[srow] = mean; iv[srow] = rsqrtf(sq*(1.f/64.f) + 1e-6f); }
    }
    __syncthreads();
  } else {
    // EMBED: issue qkv weight loads now (hidden under LN/frag build)
    if constexpr (!LAST) {
      #pragma unroll
      for (int m=0;m<3;++m){
        const short* WT = m==0?wqT:(m==1?wkT:wvT);
        const short* qp0 = WT + (size_t)(cc0 + r)*64 + kq*8;
        const short* qp1 = WT + (size_t)(cc0 + 16 + r)*64 + kq*8;
        qwb[4*m+0] = *(const bf16x8*)(qp0);
        qwb[4*m+1] = *(const bf16x8*)(qp0 + 32);
        qwb[4*m+2] = *(const bf16x8*)(qp1);
        qwb[4*m+3] = *(const bf16x8*)(qp1 + 32);
      }
    }
  }

  if constexpr (!LAST) {
    // qkv of (next) layer — weights already in registers
    const float qscale = 0.35355339059327373f;
    bf16x8 a0, a1;
    make_frags_ln(&hN[wr0+r][0], mu[wr0+r], iv[wr0+r], lns, lnb, kq, a0, a1);
    f32x4 aq[2] = {(f32x4){0,0,0,0},(f32x4){0,0,0,0}};
    f32x4 akk[2] = {(f32x4){0,0,0,0},(f32x4){0,0,0,0}};
    f32x4 av[2] = {(f32x4){0,0,0,0},(f32x4){0,0,0,0}};
    #pragma unroll
    for (int ct=0; ct<2; ++ct) {
      aq[ct]  = __builtin_amdgcn_mfma_f32_16x16x32_bf16(a0, qwb[0+2*ct],  aq[ct], 0, 0, 0);
      aq[ct]  = __builtin_amdgcn_mfma_f32_16x16x32_bf16(a1, qwb[1+2*ct],  aq[ct], 0, 0, 0);
      akk[ct] = __builtin_amdgcn_mfma_f32_16x16x32_bf16(a0, qwb[4+2*ct],  akk[ct], 0, 0, 0);
      akk[ct] = __builtin_amdgcn_mfma_f32_16x16x32_bf16(a1, qwb[5+2*ct],  akk[ct], 0, 0, 0);
      av[ct]  = __builtin_amdgcn_mfma_f32_16x16x32_bf16(a0, qwb[8+2*ct],  av[ct], 0, 0, 0);
      av[ct]  = __builtin_amdgcn_mfma_f32_16x16x32_bf16(a1, qwb[9+2*ct],  av[ct], 0, 0, 0);
    }
    #pragma unroll
    for (int ct=0; ct<2; ++ct) {
      int col = cc0 + ct*16 + r;
      float bqv = bq[col], bkv = bk[col], bvv = bv[col];
      #pragma unroll
      for (int j=0;j<4;++j) {
        size_t oi = (size_t)(row_g0 + wr0 + kq*4 + j)*DM + col;
        qo[oi] = (unsigned short)f2bf((aq[ct][j] + bqv)*qscale);
        ko[oi] = (unsigned short)f2bf(akk[ct][j] + bkv);
        vo[oi] = (unsigned short)f2bf(av[ct][j] + bvv);
      }
    }
  } else {
    // final LN (in place) + pool partial
    float mean = mu[srow], inv = iv[srow];
    #pragma unroll
    for (int i=0;i<8;++i) {
      int d = sdq*8 + i;
      hN[srow][d] = (hN[srow][d]-mean)*inv*lns[d] + lnb[d];
    }
    __syncthreads();
    if (tid < 64) {
      float s = 0.f;
      #pragma unroll 4
      for (int rr=0; rr<32; ++rr) s += hN[rr][tid];
      part[bid*64 + tid] = s;
    }
  }
}

// ---------- sliding-window attention (MFMA, unchanged) ----------
__global__ __launch_bounds__(256) void attn_kernel(
    const unsigned short* __restrict__ qg_,
    const unsigned short* __restrict__ kg_,
    const unsigned short* __restrict__ vg_,
    __hip_bfloat16* __restrict__ out)
{
  const int qblk = blockIdx.x, bh = blockIdx.y;
  const int b = bh >> 3, hh = bh & 7;
  const int tid = threadIdx.x;
  const int q0b = qblk << 7;
  const int kbase = q0b - 256;

  __shared__ unsigned short Ks[640*8];
  __shared__ unsigned short Vs[8*VSTR];

  const unsigned short* kgp = kg_ + ((size_t)b*SB)*DM + hh*8;
  const unsigned short* vgp = vg_ + ((size_t)b*SB)*DM + hh*8;

  for (int e = tid; e < 640; e += 256) {
    int g = kbase + e;
    uint4 kv = make_uint4(0,0,0,0), vv = make_uint4(0,0,0,0);
    if ((unsigned)g < (unsigned)SB) {
      kv = *(const uint4*)(kgp + (size_t)g*DM);
      vv = *(const uint4*)(vgp + (size_t)g*DM);
    }
    *(uint4*)(Ks + e*8) = kv;
    const unsigned short* pv = (const unsigned short*)&vv;
    #pragma unroll
    for (int d = 0; d < 8; ++d) Vs[d*VSTR + e] = pv[d];
  }
  __syncthreads();

  const int w = tid >> 6;
  const int lane = tid & 63;
  const int qc = lane & 31;
  const int hf = lane >> 5;
  const int qglob = q0b + 32*w + qc;

  bf16x8 qfrag = {};
  if (hf == 0) qfrag = *(const bf16x8*)(qg_ + ((size_t)b*SB + qglob)*DM + hh*8);

  f32x16 oacc = {};
  float lacc = 0.f;

  for (int t = 0; t <= 16; ++t) {
    const int k0l = 32*w + 32*t;
    const int k0g = kbase + k0l;
    if (k0g > SB-1 || k0g + 31 < 0) continue;

    bf16x8 kfrag = {};
    if (hf == 0) kfrag = *(const bf16x8*)(Ks + (k0l + qc)*8);

    f32x16 s = __builtin_amdgcn_mfma_f32_32x32x16_bf16(kfrag, qfrag, (f32x16){}, 0, 0, 0);

    float pp[16];
    bool needmask = (t == 0) | (t == 16) | (k0g < 0) | (k0g + 31 > SB-1);
    if (needmask) {
      #pragma unroll
      for (int rr = 0; rr < 16; ++rr) {
        int klg = k0g + (rr&3) + 8*(rr>>2) + 4*hf;
        bool ok = ((unsigned)(klg - qglob + 256) <= 512u) && ((unsigned)klg < (unsigned)SB);
        pp[rr] = ok ? __expf(s[rr]) : 0.f;
      }
    } else {
      #pragma unroll
      for (int rr = 0; rr < 16; ++rr) pp[rr] = __expf(s[rr]);
    }
    #pragma unroll
    for (int rr = 0; rr < 16; ++rr) lacc += pp[rr];

    unsigned pk[8];
    #pragma unroll
    for (int j = 0; j < 8; ++j) pk[j] = pack2bf(pp[2*j], pp[2*j+1]);
    unsigned sw[8];
    #pragma unroll
    for (int j = 0; j < 8; ++j) sw[j] = __shfl_xor(pk[j], 32, 64);

    union { unsigned u[4]; bf16x8 v; } pb1;
    pb1.u[0] = hf ? sw[2] : pk[0];
    pb1.u[1] = hf ? sw[3] : pk[1];
    pb1.u[2] = hf ? pk[2] : sw[0];
    pb1.u[3] = hf ? pk[3] : sw[1];
    bf16x8 va1 = {};
    if (qc < 8) va1 = *(const bf16x8*)(Vs + qc*VSTR + k0l + 8*hf);
    oacc = __builtin_amdgcn_mfma_f32_32x32x16_bf16(va1, pb1.v, oacc, 0, 0, 0);

    union { unsigned u[4]; bf16x8 v; } pb2;
    pb2.u[0] = hf ? sw[6] : pk[4];
    pb2.u[1] = hf ? sw[7] : pk[5];
    pb2.u[2] = hf ? pk[6] : sw[4];
    pb2.u[3] = hf ? pk[7] : sw[5];
    bf16x8 va2 = {};
    if (qc < 8) va2 = *(const bf16x8*)(Vs + qc*VSTR + k0l + 16 + 8*hf);
    oacc = __builtin_amdgcn_mfma_f32_32x32x16_bf16(va2, pb2.v, oacc, 0, 0, 0);
  }

  float lsum = lacc + __shfl_xor(lacc, 32, 64);
  float rcp = 1.f / lsum;
  unsigned short ov[4];
  #pragma unroll
  for (int j = 0; j < 4; ++j) ov[j] = (unsigned short)f2bf(oacc[j] * rcp);
  *(uint2*)(out + ((size_t)b*SB + qglob)*DM + hh*8 + 4*hf) = *(uint2*)ov;
}

// ---------- pool finalize + classifier ----------
__global__ __launch_bounds__(256) void pool_finalize(const float* __restrict__ part,
    const float* __restrict__ wcls, const float* __restrict__ bcls, float* __restrict__ out)
{
  int tid = threadIdx.x;
  int b = tid >> 6, d = tid & 63;
  float sum = 0.f;
  #pragma unroll 8
  for (int i = 0; i < 128; ++i) sum += part[(b*128 + i)*64 + d];
  __shared__ float pooled[4][64];
  pooled[b][d] = sum * (1.f/4096.f);
  __syncthreads();
  if (tid < 40) {
    int bb = tid / 10, c = tid % 10;
    float acc = bcls[c];
    #pragma unroll
    for (int dd = 0; dd < 64; ++dd) acc = fmaf(pooled[bb][dd], wcls[dd*10 + c], acc);
    out[tid] = acc;
  }
}

// ---------- launcher ----------
extern "C" void kernel_launch(void* const* d_in, const int* in_sizes, int n_in,
                              void* d_out, int out_size, void* d_ws, size_t ws_size,
                              hipStream_t stream)
{
  const int*   x    = (const int*)d_in[0];
  const float* emb  = (const float*)d_in[1];
  const float* wq   = (const float*)d_in[2];
  const float* bq   = (const float*)d_in[3];
  const float* wk   = (const float*)d_in[4];
  const float* bk   = (const float*)d_in[5];
  const float* wv   = (const float*)d_in[6];
  const float* bv   = (const float*)d_in[7];
  const float* wo   = (const float*)d_in[8];
  const float* bo   = (const float*)d_in[9];
  const float* ln1s = (const float*)d_in[10];
  const float* ln1b = (const float*)d_in[11];
  const float* ln2s = (const float*)d_in[12];
  const float* ln2b = (const float*)d_in[13];
  const float* w1   = (const float*)d_in[14];
  const float* b1   = (const float*)d_in[15];
  const float* w2   = (const float*)d_in[16];
  const float* b2   = (const float*)d_in[17];
  const float* lnfs = (const float*)d_in[18];
  const float* lnfb = (const float*)d_in[19];
  const float* wcls = (const float*)d_in[20];
  const float* bcls = (const float*)d_in[21];
  float* out = (float*)d_out;

  char* wsb = (char*)d_ws;
  const size_t MB = 1u << 20;
  float* h  = (float*)(wsb);                             // 4 MB f32 [16384][64]
  unsigned short* qb2 = (unsigned short*)(wsb + 4*MB);   // 2 MB bf16
  unsigned short* kb2 = (unsigned short*)(wsb + 6*MB);
  unsigned short* vb2 = (unsigned short*)(wsb + 8*MB);
  unsigned short* ab  = (unsigned short*)(wsb + 10*MB);  // 2 MB bf16
  short* wqT = (short*)(wsb + 12*MB);
  short* wkT = (short*)(wsb + 12*MB + 32*1024);
  short* wvT = (short*)(wsb + 12*MB + 64*1024);
  short* woT = (short*)(wsb + 12*MB + 96*1024);
  short* w1T = (short*)(wsb + 12*MB + 128*1024);         // 256 KB
  short* w2T = (short*)(wsb + 12*MB + 384*1024);         // 256 KB
  float* part = (float*)(wsb + 13*MB);                   // 128 KB

  wconv<<<dim3(80,4),256,0,stream>>>(wq,wk,wv,wo,w1,w2, wqT,wkT,wvT,woT,w1T,w2T);

  // head: embed + LN1(l0) + qkv(l0)
  fused_kernel<true,false><<<512,256,0,stream>>>(
      x, emb, nullptr,
      nullptr, nullptr, nullptr, nullptr,
      nullptr, nullptr, nullptr, nullptr,
      ln1s, ln1b,
      wqT, wkT, wvT, bq, bk, bv,
      qb2, kb2, vb2, h, nullptr);

  for (int l = 0; l < 4; ++l) {
    attn_kernel<<<dim3(32,32),256,0,stream>>>(qb2, kb2, vb2, (__hip_bfloat16*)ab);
    if (l < 3) {
      fused_kernel<false,false><<<512,256,0,stream>>>(
          nullptr, nullptr, ab,
          woT+4096*l, bo+64*l, ln2s+64*l, ln2b+64*l,
          w1T+32768*l, b1+512*l, w2T+32768*l, b2+64*l,
          ln1s+64*(l+1), ln1b+64*(l+1),
          wqT+4096*(l+1), wkT+4096*(l+1), wvT+4096*(l+1),
          bq+64*(l+1), bk+64*(l+1), bv+64*(l+1),
          qb2, kb2, vb2, h, nullptr);
    } else {
      fused_kernel<false,true><<<512,256,0,stream>>>(
          nullptr, nullptr, ab,
          woT+4096*l, bo+64*l, ln2s+64*l, ln2b+64*l,
          w1T+32768*l, b1+512*l, w2T+32768*l, b2+64*l,
          lnfs, lnfb,
          nullptr, nullptr, nullptr, nullptr, nullptr, nullptr,
          nullptr, nullptr, nullptr, h, part);
    }
  }
  pool_finalize<<<1,256,0,stream>>>(part, wcls, bcls, out);
}